// Round 8
// baseline (680.077 us; speedup 1.0000x reference)
//
#include <hip/hip_runtime.h>
#include <math.h>

#define IN_DIM  512
#define OUT_DIM 512
#define BATCH   2
#define NPTS    50000
#define TOTAL   (BATCH * NPTS)
#define RPW     4                        // rows per wave; 100000/4 = 25000 waves
#define NWAVES  (TOTAL / RPW)            // 25000
#define NBLK    (NWAVES / 4)             // 6250 blocks x 4 waves
#define NPROD   (BATCH * IN_DIM)         // 1024 producer waves = first 256 blocks

typedef float f4 __attribute__((ext_vector_type(4)));

__device__ __forceinline__ float dot8(f4 a0, f4 a1, f4 b0, f4 b1) {
    return a0[0]*b0[0] + a0[1]*b0[1] + a0[2]*b0[2] + a0[3]*b0[3]
         + a1[0]*b1[0] + a1[1]*b1[1] + a1[2]*b1[2] + a1[3]*b1[3];
}

__device__ __forceinline__ float wred(float x) {
    #pragma unroll
    for (int off = 32; off; off >>= 1) x += __shfl_xor(x, off);
    return x;   // full sum in ALL lanes
}

__device__ __forceinline__ float sigmoidf(float x) {
    return 1.0f / (1.0f + __expf(-x));
}

// Fused, deadlock-safe by construction (producers in the first-dispatched
// 256 blocks; consumers spin with heavy backoff via an LDS relay).
// Phase 1: waves 0..1023 compute v[b][d] = mat[d,:].s[b,:]  -> flag count.
// Phase 2: ALL waves prefetch their 4 z-rows (8KB) and PIN them in VGPRs
//          (asm) so HBM streams during the producer phase.
// Phase 3: one poller per block relays global flag -> LDS; threads wait on
//          LDS (no global poll storm: 256x less traffic than R5).
// Phase 4: load v, 4 parallel dot/reduce chains, packed lane<4 store (R6).
__global__ __launch_bounds__(256) void dgi_fused(
    const float* __restrict__ z, const float* __restrict__ s,
    const float* __restrict__ mat, float* __restrict__ out,
    float* __restrict__ v, unsigned int* __restrict__ flag)
{
    __shared__ unsigned int ready;
    if (threadIdx.x == 0) ready = 0u;
    __syncthreads();

    const int lane = threadIdx.x & 63;
    const int wid  = (int)((blockIdx.x * blockDim.x + threadIdx.x) >> 6);

    // ---- phase 1: producers (first 256 blocks) ----
    if (wid < NPROD) {
        const int b = wid >> 9;
        const int d = wid & 511;
        const f4* mrow = reinterpret_cast<const f4*>(mat + (size_t)d * OUT_DIM);
        const f4* srow = reinterpret_cast<const f4*>(s   + (size_t)b * OUT_DIM);
        const f4 m0 = mrow[lane], m1 = mrow[lane + 64];
        const f4 w0 = srow[lane], w1 = srow[lane + 64];
        const float acc = wred(dot8(m0, m1, w0, w1));
        if (lane == 0) {
            v[b * IN_DIM + d] = acc;
            __threadfence();
            __hip_atomic_fetch_add(flag, 1u, __ATOMIC_RELAXED,
                                   __HIP_MEMORY_SCOPE_AGENT);
        }
    }

    // ---- phase 2: prefetch own 4 rows (contiguous 8KB), pin in VGPRs ----
    const long r0 = (long)wid * RPW;
    const f4* zp = reinterpret_cast<const f4*>(z + r0 * IN_DIM);  // row = 128 f4
    f4 a0 = zp[lane],       a1 = zp[lane + 64];
    f4 b0 = zp[lane + 128], b1 = zp[lane + 192];
    f4 c0 = zp[lane + 256], c1 = zp[lane + 320];
    f4 d0 = zp[lane + 384], d1 = zp[lane + 448];
    asm volatile("" : "+v"(a0), "+v"(a1), "+v"(b0), "+v"(b1),
                      "+v"(c0), "+v"(c1), "+v"(d0), "+v"(d1));

    // ---- phase 3: hierarchical wait (one global poller per block) ----
    if (threadIdx.x == 0) {
        while (__hip_atomic_load(flag, __ATOMIC_RELAXED,
                                 __HIP_MEMORY_SCOPE_AGENT) < NPROD)
            __builtin_amdgcn_s_sleep(32);          // ~2000 cy backoff
        __hip_atomic_store(&ready, 1u, __ATOMIC_RELEASE,
                           __HIP_MEMORY_SCOPE_WORKGROUP);
    }
    while (__hip_atomic_load(&ready, __ATOMIC_ACQUIRE,
                             __HIP_MEMORY_SCOPE_WORKGROUP) == 0u)
        __builtin_amdgcn_s_sleep(1);
    __threadfence();   // agent-scope acquire: v now visible

    // ---- phase 4: consume ----
    const int b = (r0 >= NPTS);                    // 50000 % 4 == 0: no straddle
    const f4* vr = reinterpret_cast<const f4*>(v + (size_t)b * IN_DIM);
    const f4 v0 = vr[lane], v1 = vr[lane + 64];

    const float rA = wred(dot8(a0, a1, v0, v1));
    const float rB = wred(dot8(b0, b1, v0, v1));
    const float rC = wred(dot8(c0, c1, v0, v1));
    const float rD = wred(dot8(d0, d1, v0, v1));

    const float r = (lane == 0) ? rA : (lane == 1) ? rB : (lane == 2) ? rC : rD;
    if (lane < 4) out[r0 + lane] = sigmoidf(r);
}

extern "C" void kernel_launch(void* const* d_in, const int* in_sizes, int n_in,
                              void* d_out, int out_size, void* d_ws, size_t ws_size,
                              hipStream_t stream) {
    const float* z   = (const float*)d_in[0];   // [2, 50000, 512] f32
    const float* s   = (const float*)d_in[1];   // [2, 512] f32
    const float* mat = (const float*)d_in[2];   // [512, 512] f32
    float* out = (float*)d_out;                 // [2, 50000] f32

    float*        v    = (float*)d_ws;                          // 4 KB
    unsigned int* flag = (unsigned int*)((char*)d_ws + 4096);   // 4 B

    // flag must be 0 at kernel start on every replay (graph-capture legal)
    hipMemsetAsync(flag, 0, sizeof(unsigned int), stream);

    dgi_fused<<<NBLK, 256, 0, stream>>>(z, s, mat, out, v, flag);
}

// Round 9
// 38.806 us; speedup vs baseline: 17.5251x; 17.5251x over previous
//
#include <hip/hip_runtime.h>
#include <math.h>

#define IN_DIM  512
#define OUT_DIM 512
#define BATCH   2
#define NPTS    50000
#define TOTAL   (BATCH * NPTS)
#define RPW     4                        // rows per wave; 100000/4 = 25000 waves exact
#define NWAVES  (TOTAL / RPW)            // 25000
#define NBLK    (NWAVES / 4)             // 6250 blocks x 4 waves

typedef float f4 __attribute__((ext_vector_type(4)));

__device__ __forceinline__ float dot8(f4 a0, f4 a1, f4 b0, f4 b1) {
    return a0[0]*b0[0] + a0[1]*b0[1] + a0[2]*b0[2] + a0[3]*b0[3]
         + a1[0]*b1[0] + a1[1]*b1[1] + a1[2]*b1[2] + a1[3]*b1[3];
}

__device__ __forceinline__ float wred(float x) {
    #pragma unroll
    for (int off = 32; off; off >>= 1) x += __shfl_xor(x, off);
    return x;   // full sum in ALL lanes
}

__device__ __forceinline__ float sigmoidf(float x) {
    return 1.0f / (1.0f + __expf(-x));
}

// Kernel 1: v[b][d] = sum_e mat[d][e] * s[b][e]   (v: [2][512] f32 in d_ws)
// 1024 waves, one per (b,d). s is 4 KB -> L2-resident, mat rows coalesced f4.
__global__ __launch_bounds__(256) void dgi_compute_v(
    const float* __restrict__ mat, const float* __restrict__ s,
    float* __restrict__ v)
{
    const int lane = threadIdx.x & 63;
    const int W    = (int)((blockIdx.x * blockDim.x + threadIdx.x) >> 6);
    const int b    = W >> 9;
    const int d    = W & 511;

    const f4* mrow = reinterpret_cast<const f4*>(mat + (size_t)d * OUT_DIM);
    const f4* srow = reinterpret_cast<const f4*>(s   + (size_t)b * OUT_DIM);
    const f4 m0 = mrow[lane], m1 = mrow[lane + 64];
    const f4 s0 = srow[lane], s1 = srow[lane + 64];

    float acc = wred(dot8(m0, m1, s0, s1));
    if (lane == 0) v[b * IN_DIM + d] = acc;
}

// Kernel 2: out[row] = sigmoid( z[row,:] . v[b,:] ), b = row >= NPTS.
// Measured-best structure (R6, 38.48us): 25000 identical SHORT waves, each
// exactly 4 contiguous rows (8 KB), no loop. 8 independent float4 loads in
// flight, 4 parallel reduce chains, one packed 16B store. No remainder, no
// batch straddle (50000 % 4 == 0).
__global__ __launch_bounds__(256) void dgi_score(
    const float* __restrict__ z, const float* __restrict__ v,
    float* __restrict__ out)
{
    const int lane = threadIdx.x & 63;
    const int wid  = (int)((blockIdx.x * blockDim.x + threadIdx.x) >> 6);

    const long r0 = (long)wid * RPW;         // 4 contiguous rows, one batch
    const int  b  = (r0 >= NPTS);

    const f4* vr = reinterpret_cast<const f4*>(v + (size_t)b * IN_DIM);
    const f4 v0 = vr[lane], v1 = vr[lane + 64];

    const f4* zp = reinterpret_cast<const f4*>(z + r0 * IN_DIM);  // row = 128 f4
    const f4 a0 = zp[lane],       a1 = zp[lane + 64];
    const f4 b0 = zp[lane + 128], b1 = zp[lane + 192];
    const f4 c0 = zp[lane + 256], c1 = zp[lane + 320];
    const f4 d0 = zp[lane + 384], d1 = zp[lane + 448];

    const float rA = wred(dot8(a0, a1, v0, v1));
    const float rB = wred(dot8(b0, b1, v0, v1));
    const float rC = wred(dot8(c0, c1, v0, v1));
    const float rD = wred(dot8(d0, d1, v0, v1));

    // packed epilogue: lanes 0-3 store the 4 results (one 16B-wide store)
    const float r = (lane == 0) ? rA : (lane == 1) ? rB : (lane == 2) ? rC : rD;
    if (lane < 4) out[r0 + lane] = sigmoidf(r);
}

extern "C" void kernel_launch(void* const* d_in, const int* in_sizes, int n_in,
                              void* d_out, int out_size, void* d_ws, size_t ws_size,
                              hipStream_t stream) {
    const float* z   = (const float*)d_in[0];   // [2, 50000, 512] f32
    const float* s   = (const float*)d_in[1];   // [2, 512] f32
    const float* mat = (const float*)d_in[2];   // [512, 512] f32
    float* out = (float*)d_out;                 // [2, 50000] f32
    float* v   = (float*)d_ws;                  // [2, 512] f32 scratch

    dgi_compute_v<<<BATCH * 128, 256, 0, stream>>>(mat, s, v);
    dgi_score<<<NBLK, 256, 0, stream>>>(z, v, out);
}